// Round 3
// baseline (2705.810 us; speedup 1.0000x reference)
//
#include <hip/hip_runtime.h>

#define N_NODES 50000

// ---------------- degree / norm / CSR build ----------------
// NOTE: harness delivers integer inputs as int32 (even though the JAX ref
// declares int64) — reading as long long was the R1/R2 crash.

__global__ void degree_kernel(const int* __restrict__ ei,
                              int* __restrict__ deg_out, int* __restrict__ deg_in, int E) {
    int e = blockIdx.x * blockDim.x + threadIdx.x;
    if (e >= E) return;
    int s = ei[e];
    int d = ei[E + e];
    if (s >= 0 && s < N_NODES) atomicAdd(&deg_out[s], 1);
    if (d >= 0 && d < N_NODES) atomicAdd(&deg_in[d], 1);
}

__global__ void dinv_kernel(const int* __restrict__ deg_out, const int* __restrict__ deg_in,
                            float* __restrict__ dinv_out, float* __restrict__ dinv_in, int n) {
    int v = blockIdx.x * blockDim.x + threadIdx.x;
    if (v >= n) return;
    dinv_out[v] = rsqrtf((float)max(deg_out[v], 1));
    dinv_in[v]  = rsqrtf((float)max(deg_in[v], 1));
}

// exclusive scan of deg_in -> row_start[0..n], single block of 1024
__global__ void scan_kernel(const int* __restrict__ deg, int* __restrict__ row_start, int n) {
    __shared__ int sdata[1024];
    __shared__ int carry;
    int tid = threadIdx.x;
    if (tid == 0) { carry = 0; row_start[0] = 0; }
    __syncthreads();
    for (int base = 0; base < n; base += 1024) {
        int i = base + tid;
        int v = (i < n) ? deg[i] : 0;
        sdata[tid] = v;
        __syncthreads();
        for (int off = 1; off < 1024; off <<= 1) {
            int t = (tid >= off) ? sdata[tid - off] : 0;
            __syncthreads();
            sdata[tid] += t;
            __syncthreads();
        }
        if (i < n) row_start[i + 1] = carry + sdata[tid];
        __syncthreads();
        if (tid == 0) carry += sdata[1023];
        __syncthreads();
    }
}

__global__ void fill_kernel(const int* __restrict__ ei, const int* __restrict__ row_start,
                            int* __restrict__ fill_cnt, int* __restrict__ csr_src, int E) {
    int e = blockIdx.x * blockDim.x + threadIdx.x;
    if (e >= E) return;
    int s = ei[e];
    int d = ei[E + e];
    if (d < 0 || d >= N_NODES) return;
    int pos = row_start[d] + atomicAdd(&fill_cnt[d], 1);
    csr_src[pos] = s;
}

// ---------------- GEMM: H = (A [* dinv_out]) @ W  [+ bias] [leaky] ----------------
// A: [M,K] row-major, W: [K,N] row-major, H: [M,N]. 64x64 tile, BK=16, 256 thr.

template <bool SCALE_A>
__global__ __launch_bounds__(256) void gemm_kernel(
    const float* __restrict__ A, const float* __restrict__ dinv,
    const float* __restrict__ W, float* __restrict__ H,
    const float* __restrict__ bias, int relu,
    int M, int K, int N)
{
    __shared__ float As[16][68];  // [k][m], +4 pad
    __shared__ float Bs[16][64];  // [k][n]

    int tid = threadIdx.x;
    int bm = blockIdx.x * 64;
    int bn = blockIdx.y * 64;

    int a_row = tid >> 2;          // 0..63
    int a_k   = (tid & 3) << 2;    // 0,4,8,12
    int b_row = tid >> 4;          // 0..15
    int b_col = (tid & 15) << 2;   // 0..60
    int tx = tid & 15, ty = tid >> 4;

    float acc[4][4] = {};

    int gr = bm + a_row;
    bool arow_ok = (gr < M);
    float dscale = 1.0f;
    if (SCALE_A) dscale = arow_ok ? dinv[gr] : 0.f;
    const float* arow = A + (size_t)(arow_ok ? gr : 0) * K;
    const float* wrow = W + (size_t)b_row * N + bn + b_col;

    for (int kt = 0; kt < K; kt += 16) {
        float4 av = make_float4(0.f, 0.f, 0.f, 0.f);
        int gk = kt + a_k;
        if (arow_ok && gk < K)   // all K are %4==0, so gk<K implies full float4 in-range
            av = *reinterpret_cast<const float4*>(arow + gk);
        As[a_k + 0][a_row] = av.x * dscale;
        As[a_k + 1][a_row] = av.y * dscale;
        As[a_k + 2][a_row] = av.z * dscale;
        As[a_k + 3][a_row] = av.w * dscale;

        float4 bv = make_float4(0.f, 0.f, 0.f, 0.f);
        int gkb = kt + b_row;
        if (gkb < K)
            bv = *reinterpret_cast<const float4*>(wrow + (size_t)kt * N);
        *reinterpret_cast<float4*>(&Bs[b_row][b_col]) = bv;

        __syncthreads();
        #pragma unroll
        for (int k = 0; k < 16; ++k) {
            float4 a4 = *reinterpret_cast<const float4*>(&As[k][ty * 4]);
            float4 b4 = *reinterpret_cast<const float4*>(&Bs[k][tx * 4]);
            float a[4] = {a4.x, a4.y, a4.z, a4.w};
            float b[4] = {b4.x, b4.y, b4.z, b4.w};
            #pragma unroll
            for (int i = 0; i < 4; ++i)
                #pragma unroll
                for (int j = 0; j < 4; ++j)
                    acc[i][j] += a[i] * b[j];
        }
        __syncthreads();
    }

    float bcol[4] = {0.f, 0.f, 0.f, 0.f};
    if (bias) {
        float4 b4 = *reinterpret_cast<const float4*>(bias + bn + tx * 4);
        bcol[0] = b4.x; bcol[1] = b4.y; bcol[2] = b4.z; bcol[3] = b4.w;
    }
    #pragma unroll
    for (int i = 0; i < 4; ++i) {
        int r = bm + ty * 4 + i;
        if (r < M) {
            float o[4];
            #pragma unroll
            for (int j = 0; j < 4; ++j) {
                float t = acc[i][j] + bcol[j];
                if (relu) t = (t > 0.f) ? t : 0.01f * t;
                o[j] = t;
            }
            *reinterpret_cast<float4*>(H + (size_t)r * N + bn + tx * 4) =
                make_float4(o[0], o[1], o[2], o[3]);
        }
    }
}

// ---------------- SpMM ----------------
// PRE  (agg-first): out[v] = (sum_u X[u]*dinv_out[u]) * dinv_in[v]
// POST (W-first)  : out[v] = (sum_u H[u]) * dinv_in[v] + bias, optional leaky

template <bool PRE>
__global__ void spmm_kernel(
    const float* __restrict__ H, const int* __restrict__ row_start,
    const int* __restrict__ csr_src,
    const float* __restrict__ dinv_out, const float* __restrict__ dinv_in,
    const float* __restrict__ bias, int relu,
    float* __restrict__ out, int fo)
{
    int v = blockIdx.x;
    int col = blockIdx.y * blockDim.x + threadIdx.x;
    if (col >= fo) return;
    int s = row_start[v], e = row_start[v + 1];
    float acc = 0.f;
    for (int i = s; i < e; ++i) {
        int u = csr_src[i];
        float h = H[(size_t)u * fo + col];
        if (PRE) h *= dinv_out[u];
        acc += h;
    }
    float r = acc * dinv_in[v];
    if (!PRE) {
        r += bias[col];
        if (relu) r = (r > 0.f) ? r : 0.01f * r;
    }
    out[(size_t)v * fo + col] = r;
}

// ---------------- launch ----------------

extern "C" void kernel_launch(void* const* d_in, const int* in_sizes, int n_in,
                              void* d_out, int out_size, void* d_ws, size_t ws_size,
                              hipStream_t stream) {
    const float* x = (const float*)d_in[0];
    const int* ei = (const int*)d_in[1];           // int32! (harness contract)
    const float* Wm[5] = {(const float*)d_in[2], (const float*)d_in[4], (const float*)d_in[6],
                          (const float*)d_in[8], (const float*)d_in[10]};
    const float* bv[5] = {(const float*)d_in[3], (const float*)d_in[5], (const float*)d_in[7],
                          (const float*)d_in[9], (const float*)d_in[11]};
    const int E = in_sizes[1] / 2;                 // 250000
    const int M = N_NODES;
    float* out = (float*)d_out;

    // ---- d_ws layout (int units). Total use ≈ 2.2MB CSR + 25.6MB buffer @4MB.
    int* wsi = (int*)d_ws;
    int* deg_out   = wsi + 0;
    int* deg_in    = wsi + 50048;
    int* fill_cnt  = wsi + 100096;
    int* row_start = wsi + 150144;  // 50001 ints
    int* csr_src   = wsi + 200256;  // 250000 ints
    float* dinv_out = (float*)(wsi + 450304);
    float* dinv_in  = (float*)(wsi + 500352);
    float* ws_small = (float*)wsi + (size_t)1024 * 1024;  // 4MB offset; M*128 floats

    // Big ping-pong halves live inside d_out (capacity M*2048 floats).
    float* outA = out;                       // M*1024 floats
    float* outB = out + (size_t)M * 1024;    // M*1024 floats

    // zero deg_out, deg_in, fill_cnt (contiguous [0, 150144) ints)
    hipMemsetAsync(d_ws, 0, (size_t)150144 * 4, stream);

    degree_kernel<<<(E + 255) / 256, 256, 0, stream>>>(ei, deg_out, deg_in, E);
    dinv_kernel<<<(M + 255) / 256, 256, 0, stream>>>(deg_out, deg_in, dinv_out, dinv_in, M);
    scan_kernel<<<1, 1024, 0, stream>>>(deg_in, row_start, M);
    fill_kernel<<<(E + 255) / 256, 256, 0, stream>>>(ei, row_start, fill_cnt, csr_src, E);

    // L1 (300->1024), agg-first: spmm_pre(x)->outB[:,:300] ; gemm(+b1,relu)->outA
    {
        dim3 sg(M, 2);
        spmm_kernel<true><<<sg, 256, 0, stream>>>(x, row_start, csr_src, dinv_out, dinv_in,
                                                  nullptr, 0, outB, 300);
        dim3 gg((M + 63) / 64, 1024 / 64);
        gemm_kernel<false><<<gg, 256, 0, stream>>>(outB, nullptr, Wm[0], outA, bv[0], 1, M, 300, 1024);
    }
    // L2-L4, W-first: gemm_scaleA(outA)->outB ; spmm_post(outB)->outA
    const int dims_mid[4] = {1024, 512, 256, 128};
    for (int l = 1; l <= 3; ++l) {
        int K = dims_mid[l - 1], No = dims_mid[l];
        dim3 gg((M + 63) / 64, No / 64);
        gemm_kernel<true><<<gg, 256, 0, stream>>>(outA, dinv_out, Wm[l], outB, nullptr, 0, M, K, No);
        int blk = (No >= 256) ? 256 : No;
        dim3 sg(M, (No + blk - 1) / blk);
        spmm_kernel<false><<<sg, blk, 0, stream>>>(outB, row_start, csr_src, nullptr, dinv_in,
                                                   bv[l], 1, outA, No);
    }
    // L5 (128->2048), agg-first: spmm_pre(outA,128)->ws_small ; gemm->out (full)
    {
        dim3 sg(M, 1);
        spmm_kernel<true><<<sg, 128, 0, stream>>>(outA, row_start, csr_src, dinv_out, dinv_in,
                                                  nullptr, 0, ws_small, 128);
        dim3 gg((M + 63) / 64, 2048 / 64);
        gemm_kernel<false><<<gg, 256, 0, stream>>>(ws_small, nullptr, Wm[4], out, bv[4], 0, M, 128, 2048);
    }
}

// Round 4
// 2633.110 us; speedup vs baseline: 1.0276x; 1.0276x over previous
//
#include <hip/hip_runtime.h>

#define N_NODES 50000

// ---------------- degree / norm / CSR build ----------------
// NOTE: harness delivers integer inputs as int32 (R1/R2 crash root-cause).

__global__ void degree_kernel(const int* __restrict__ ei,
                              int* __restrict__ deg_out, int* __restrict__ deg_in, int E) {
    int e = blockIdx.x * blockDim.x + threadIdx.x;
    if (e >= E) return;
    int s = ei[e];
    int d = ei[E + e];
    if (s >= 0 && s < N_NODES) atomicAdd(&deg_out[s], 1);
    if (d >= 0 && d < N_NODES) atomicAdd(&deg_in[d], 1);
}

__global__ void dinv_kernel(const int* __restrict__ deg_out, const int* __restrict__ deg_in,
                            float* __restrict__ dinv_out, float* __restrict__ dinv_in, int n) {
    int v = blockIdx.x * blockDim.x + threadIdx.x;
    if (v >= n) return;
    dinv_out[v] = rsqrtf((float)max(deg_out[v], 1));
    dinv_in[v]  = rsqrtf((float)max(deg_in[v], 1));
}

// exclusive scan of deg_in -> row_start[0..n], single block of 1024
__global__ void scan_kernel(const int* __restrict__ deg, int* __restrict__ row_start, int n) {
    __shared__ int sdata[1024];
    __shared__ int carry;
    int tid = threadIdx.x;
    if (tid == 0) { carry = 0; row_start[0] = 0; }
    __syncthreads();
    for (int base = 0; base < n; base += 1024) {
        int i = base + tid;
        int v = (i < n) ? deg[i] : 0;
        sdata[tid] = v;
        __syncthreads();
        for (int off = 1; off < 1024; off <<= 1) {
            int t = (tid >= off) ? sdata[tid - off] : 0;
            __syncthreads();
            sdata[tid] += t;
            __syncthreads();
        }
        if (i < n) row_start[i + 1] = carry + sdata[tid];
        __syncthreads();
        if (tid == 0) carry += sdata[1023];
        __syncthreads();
    }
}

__global__ void fill_kernel(const int* __restrict__ ei, const int* __restrict__ row_start,
                            int* __restrict__ fill_cnt, int* __restrict__ csr_src, int E) {
    int e = blockIdx.x * blockDim.x + threadIdx.x;
    if (e >= E) return;
    int s = ei[e];
    int d = ei[E + e];
    if (d < 0 || d >= N_NODES) return;
    int pos = row_start[d] + atomicAdd(&fill_cnt[d], 1);
    csr_src[pos] = s;
}

// ---------------- GEMM v2: 128x128 tile, BK=16, 256 thr, 8x8 acc ----------------
// H = (A [* dinv_out]) @ W [+ bias] [leaky]
// A: [M,K] row-major, W: [K,N] row-major (N % 128 == 0), H: [M,N].
// Per-thread fragment split as {base, base+64} in both m and n so LDS reads
// are 16B-stride across lanes (conflict-free) and C-writes stay coalesced.

template <bool SCALE_A>
__global__ __launch_bounds__(256) void gemm128_kernel(
    const float* __restrict__ A, const float* __restrict__ dinv,
    const float* __restrict__ W, float* __restrict__ H,
    const float* __restrict__ bias, int relu,
    int M, int K, int N)
{
    __shared__ float As[16][132];  // [k][m], +4 pad
    __shared__ float Bs[16][132];  // [k][n], +4 pad

    int tid = threadIdx.x;
    int bm = blockIdx.x * 128;
    int bn = blockIdx.y * 128;
    int tx = tid & 15, ty = tid >> 4;

    float acc[8][8];
    #pragma unroll
    for (int i = 0; i < 8; ++i)
        #pragma unroll
        for (int j = 0; j < 8; ++j) acc[i][j] = 0.f;

    // A staging map: thread t -> m = t>>1 (0..127), k4 = (t&1)*8 ; two float4
    int am = tid >> 1;
    int ak = (tid & 1) * 8;
    int gr = bm + am;
    bool arow_ok = (gr < M);
    float dscale = 1.0f;
    if (SCALE_A) dscale = arow_ok ? dinv[gr] : 0.f;
    const float* arow = A + (size_t)(arow_ok ? gr : 0) * K;

    // B staging map: thread t -> k = t>>4 (0..15), two float4 cols c and c+16
    int bk = tid >> 4;
    int bc = tid & 15;
    const float* wbase = W + bn;

    for (int kt = 0; kt < K; kt += 16) {
        // ---- stage A (transpose to [k][m], scaled) ----
        {
            float4 av0 = make_float4(0.f, 0.f, 0.f, 0.f);
            float4 av1 = make_float4(0.f, 0.f, 0.f, 0.f);
            int gk0 = kt + ak;
            int gk1 = kt + ak + 4;
            if (arow_ok && gk0 < K) av0 = *reinterpret_cast<const float4*>(arow + gk0);  // K%4==0
            if (arow_ok && gk1 < K) av1 = *reinterpret_cast<const float4*>(arow + gk1);
            As[ak + 0][am] = av0.x * dscale;
            As[ak + 1][am] = av0.y * dscale;
            As[ak + 2][am] = av0.z * dscale;
            As[ak + 3][am] = av0.w * dscale;
            As[ak + 4][am] = av1.x * dscale;
            As[ak + 5][am] = av1.y * dscale;
            As[ak + 6][am] = av1.z * dscale;
            As[ak + 7][am] = av1.w * dscale;
        }
        // ---- stage B ----
        {
            int gk = kt + bk;
            float4 bv0 = make_float4(0.f, 0.f, 0.f, 0.f);
            float4 bv1 = make_float4(0.f, 0.f, 0.f, 0.f);
            if (gk < K) {
                const float* wrow = wbase + (size_t)gk * N;
                bv0 = *reinterpret_cast<const float4*>(wrow + bc * 4);
                bv1 = *reinterpret_cast<const float4*>(wrow + 64 + bc * 4);
            }
            *reinterpret_cast<float4*>(&Bs[bk][bc * 4]) = bv0;
            *reinterpret_cast<float4*>(&Bs[bk][64 + bc * 4]) = bv1;
        }
        __syncthreads();

        #pragma unroll
        for (int k = 0; k < 16; ++k) {
            float4 a0 = *reinterpret_cast<const float4*>(&As[k][ty * 4]);
            float4 a1 = *reinterpret_cast<const float4*>(&As[k][64 + ty * 4]);
            float4 b0 = *reinterpret_cast<const float4*>(&Bs[k][tx * 4]);
            float4 b1 = *reinterpret_cast<const float4*>(&Bs[k][64 + tx * 4]);
            float a[8] = {a0.x, a0.y, a0.z, a0.w, a1.x, a1.y, a1.z, a1.w};
            float b[8] = {b0.x, b0.y, b0.z, b0.w, b1.x, b1.y, b1.z, b1.w};
            #pragma unroll
            for (int i = 0; i < 8; ++i)
                #pragma unroll
                for (int j = 0; j < 8; ++j)
                    acc[i][j] += a[i] * b[j];
        }
        __syncthreads();
    }

    // ---- epilogue ----
    float bcol[8] = {0.f, 0.f, 0.f, 0.f, 0.f, 0.f, 0.f, 0.f};
    if (bias) {
        float4 c0 = *reinterpret_cast<const float4*>(bias + bn + tx * 4);
        float4 c1 = *reinterpret_cast<const float4*>(bias + bn + 64 + tx * 4);
        bcol[0] = c0.x; bcol[1] = c0.y; bcol[2] = c0.z; bcol[3] = c0.w;
        bcol[4] = c1.x; bcol[5] = c1.y; bcol[6] = c1.z; bcol[7] = c1.w;
    }
    #pragma unroll
    for (int i = 0; i < 8; ++i) {
        int r = bm + ((i < 4) ? (ty * 4 + i) : (64 + ty * 4 + i - 4));
        if (r < M) {
            float o[8];
            #pragma unroll
            for (int j = 0; j < 8; ++j) {
                float t = acc[i][j] + bcol[j];
                if (relu) t = (t > 0.f) ? t : 0.01f * t;
                o[j] = t;
            }
            float* hrow = H + (size_t)r * N + bn;
            *reinterpret_cast<float4*>(hrow + tx * 4)      = make_float4(o[0], o[1], o[2], o[3]);
            *reinterpret_cast<float4*>(hrow + 64 + tx * 4) = make_float4(o[4], o[5], o[6], o[7]);
        }
    }
}

// ---------------- SpMM ----------------
// PRE  (agg-first): out[v] = (sum_u X[u]*dinv_out[u]) * dinv_in[v]
// POST (W-first)  : out[v] = (sum_u H[u]) * dinv_in[v] + bias, optional leaky

template <bool PRE>
__global__ void spmm_kernel(
    const float* __restrict__ H, const int* __restrict__ row_start,
    const int* __restrict__ csr_src,
    const float* __restrict__ dinv_out, const float* __restrict__ dinv_in,
    const float* __restrict__ bias, int relu,
    float* __restrict__ out, int fo)
{
    int v = blockIdx.x;
    int col = blockIdx.y * blockDim.x + threadIdx.x;
    if (col >= fo) return;
    int s = row_start[v], e = row_start[v + 1];
    float acc = 0.f;
    for (int i = s; i < e; ++i) {
        int u = csr_src[i];
        float h = H[(size_t)u * fo + col];
        if (PRE) h *= dinv_out[u];
        acc += h;
    }
    float r = acc * dinv_in[v];
    if (!PRE) {
        r += bias[col];
        if (relu) r = (r > 0.f) ? r : 0.01f * r;
    }
    out[(size_t)v * fo + col] = r;
}

// ---------------- launch ----------------

extern "C" void kernel_launch(void* const* d_in, const int* in_sizes, int n_in,
                              void* d_out, int out_size, void* d_ws, size_t ws_size,
                              hipStream_t stream) {
    const float* x = (const float*)d_in[0];
    const int* ei = (const int*)d_in[1];           // int32 (harness contract)
    const float* Wm[5] = {(const float*)d_in[2], (const float*)d_in[4], (const float*)d_in[6],
                          (const float*)d_in[8], (const float*)d_in[10]};
    const float* bv[5] = {(const float*)d_in[3], (const float*)d_in[5], (const float*)d_in[7],
                          (const float*)d_in[9], (const float*)d_in[11]};
    const int E = in_sizes[1] / 2;                 // 250000
    const int M = N_NODES;
    float* out = (float*)d_out;

    // ---- d_ws layout (int units). ~2.2MB CSR + 25.6MB buffer @4MB.
    int* wsi = (int*)d_ws;
    int* deg_out   = wsi + 0;
    int* deg_in    = wsi + 50048;
    int* fill_cnt  = wsi + 100096;
    int* row_start = wsi + 150144;  // 50001 ints
    int* csr_src   = wsi + 200256;  // 250000 ints
    float* dinv_out = (float*)(wsi + 450304);
    float* dinv_in  = (float*)(wsi + 500352);
    float* ws_small = (float*)wsi + (size_t)1024 * 1024;  // 4MB offset; M*128 floats

    // Big ping-pong halves live inside d_out (capacity M*2048 floats).
    float* outA = out;                       // M*1024 floats
    float* outB = out + (size_t)M * 1024;    // M*1024 floats

    hipMemsetAsync(d_ws, 0, (size_t)150144 * 4, stream);

    degree_kernel<<<(E + 255) / 256, 256, 0, stream>>>(ei, deg_out, deg_in, E);
    dinv_kernel<<<(M + 255) / 256, 256, 0, stream>>>(deg_out, deg_in, dinv_out, dinv_in, M);
    scan_kernel<<<1, 1024, 0, stream>>>(deg_in, row_start, M);
    fill_kernel<<<(E + 255) / 256, 256, 0, stream>>>(ei, row_start, fill_cnt, csr_src, E);

    const int MB = (M + 127) / 128;  // 391

    // L1 (300->1024), agg-first: spmm_pre(x)->outB[:,:300] ; gemm(+b1,relu)->outA
    {
        dim3 sg(M, 2);
        spmm_kernel<true><<<sg, 256, 0, stream>>>(x, row_start, csr_src, dinv_out, dinv_in,
                                                  nullptr, 0, outB, 300);
        dim3 gg(MB, 1024 / 128);
        gemm128_kernel<false><<<gg, 256, 0, stream>>>(outB, nullptr, Wm[0], outA, bv[0], 1,
                                                      M, 300, 1024);
    }
    // L2-L4, W-first: gemm_scaleA(outA)->outB ; spmm_post(outB)->outA
    const int dims_mid[4] = {1024, 512, 256, 128};
    for (int l = 1; l <= 3; ++l) {
        int K = dims_mid[l - 1], No = dims_mid[l];
        dim3 gg(MB, No / 128);
        gemm128_kernel<true><<<gg, 256, 0, stream>>>(outA, dinv_out, Wm[l], outB, nullptr, 0,
                                                     M, K, No);
        int blk = (No >= 256) ? 256 : No;
        dim3 sg(M, (No + blk - 1) / blk);
        spmm_kernel<false><<<sg, blk, 0, stream>>>(outB, row_start, csr_src, nullptr, dinv_in,
                                                   bv[l], 1, outA, No);
    }
    // L5 (128->2048), agg-first: spmm_pre(outA,128)->ws_small ; gemm->out (full)
    {
        dim3 sg(M, 1);
        spmm_kernel<true><<<sg, 128, 0, stream>>>(outA, row_start, csr_src, dinv_out, dinv_in,
                                                  nullptr, 0, ws_small, 128);
        dim3 gg(MB, 2048 / 128);
        gemm128_kernel<false><<<gg, 256, 0, stream>>>(ws_small, nullptr, Wm[4], out, bv[4], 0,
                                                      M, 128, 2048);
    }
}

// Round 5
// 1696.835 us; speedup vs baseline: 1.5946x; 1.5518x over previous
//
#include <hip/hip_runtime.h>

#define N_NODES 50000

typedef __attribute__((ext_vector_type(8))) short short8v;
typedef __attribute__((ext_vector_type(4))) float f32x4;
typedef unsigned int u32;
typedef unsigned short u16;

__device__ inline u16 bf16_rn(float a) {
    u32 u = __float_as_uint(a);
    return (u16)((u + 0x7FFFu + ((u >> 16) & 1u)) >> 16);
}
__device__ inline void bf16_split(float a, u16& h, u16& l) {
    h = bf16_rn(a);
    float hf = __uint_as_float(((u32)h) << 16);
    l = bf16_rn(a - hf);
}

// ---------------- degree / norm / CSR build ----------------

__global__ void degree_kernel(const int* __restrict__ ei,
                              int* __restrict__ deg_out, int* __restrict__ deg_in, int E) {
    int e = blockIdx.x * blockDim.x + threadIdx.x;
    if (e >= E) return;
    int s = ei[e];
    int d = ei[E + e];
    if (s >= 0 && s < N_NODES) atomicAdd(&deg_out[s], 1);
    if (d >= 0 && d < N_NODES) atomicAdd(&deg_in[d], 1);
}

__global__ void dinv_kernel(const int* __restrict__ deg_out, const int* __restrict__ deg_in,
                            float* __restrict__ dinv_out, float* __restrict__ dinv_in, int n) {
    int v = blockIdx.x * blockDim.x + threadIdx.x;
    if (v >= n) return;
    dinv_out[v] = rsqrtf((float)max(deg_out[v], 1));
    dinv_in[v]  = rsqrtf((float)max(deg_in[v], 1));
}

__global__ void scan_kernel(const int* __restrict__ deg, int* __restrict__ row_start, int n) {
    __shared__ int sdata[1024];
    __shared__ int carry;
    int tid = threadIdx.x;
    if (tid == 0) { carry = 0; row_start[0] = 0; }
    __syncthreads();
    for (int base = 0; base < n; base += 1024) {
        int i = base + tid;
        int v = (i < n) ? deg[i] : 0;
        sdata[tid] = v;
        __syncthreads();
        for (int off = 1; off < 1024; off <<= 1) {
            int t = (tid >= off) ? sdata[tid - off] : 0;
            __syncthreads();
            sdata[tid] += t;
            __syncthreads();
        }
        if (i < n) row_start[i + 1] = carry + sdata[tid];
        __syncthreads();
        if (tid == 0) carry += sdata[1023];
        __syncthreads();
    }
}

__global__ void fill_kernel(const int* __restrict__ ei, const int* __restrict__ row_start,
                            int* __restrict__ fill_cnt, int* __restrict__ csr_src, int E) {
    int e = blockIdx.x * blockDim.x + threadIdx.x;
    if (e >= E) return;
    int s = ei[e];
    int d = ei[E + e];
    if (d < 0 || d >= N_NODES) return;
    int pos = row_start[d] + atomicAdd(&fill_cnt[d], 1);
    csr_src[pos] = s;
}

// ---------------- W split+transpose: W[K][N] f32 -> Wt_hi/lo [N][Kp] bf16 ----------------

__global__ __launch_bounds__(256) void wsplit_kernel(
    const float* __restrict__ W, u16* __restrict__ Thi, u16* __restrict__ Tlo,
    int K, int Kp, int N)
{
    __shared__ float Ts[32][73];
    int tid = threadIdx.x;
    int k0 = blockIdx.x * 32, n0 = blockIdx.y * 64;
    int kk = tid >> 3, nn = (tid & 7) * 8;
    float4 v0 = make_float4(0.f, 0.f, 0.f, 0.f), v1 = v0;
    if (k0 + kk < K) {
        const float* p = W + (size_t)(k0 + kk) * N + n0 + nn;
        v0 = *reinterpret_cast<const float4*>(p);
        v1 = *reinterpret_cast<const float4*>(p + 4);
    }
    Ts[kk][nn + 0] = v0.x; Ts[kk][nn + 1] = v0.y; Ts[kk][nn + 2] = v0.z; Ts[kk][nn + 3] = v0.w;
    Ts[kk][nn + 4] = v1.x; Ts[kk][nn + 5] = v1.y; Ts[kk][nn + 6] = v1.z; Ts[kk][nn + 7] = v1.w;
    __syncthreads();
    int n = tid >> 2, kq = (tid & 3) * 8;
    union { u16 a[8]; uint4 q; } Uh, Ul;
    #pragma unroll
    for (int e = 0; e < 8; ++e) {
        u16 h, l;
        bf16_split(Ts[kq + e][n], h, l);
        Uh.a[e] = h; Ul.a[e] = l;
    }
    size_t off = (size_t)(n0 + n) * Kp + k0 + kq;
    *reinterpret_cast<uint4*>(Thi + off) = Uh.q;
    *reinterpret_cast<uint4*>(Tlo + off) = Ul.q;
}

// ---------------- SpMM variants ----------------
// pre: r = (sum_u X[u][col] * (WEIGH? dinv_out[u] : 1)) * dinv_in[v]; write bf16 hi/lo
template <bool WEIGH>
__global__ void spmm_pre_split(
    const float* __restrict__ X, const int* __restrict__ row_start,
    const int* __restrict__ csr_src,
    const float* __restrict__ dinv_out, const float* __restrict__ dinv_in,
    u16* __restrict__ Ohi, u16* __restrict__ Olo, int fo, int fopad)
{
    int v = blockIdx.x;
    int col = blockIdx.y * blockDim.x + threadIdx.x;
    if (col >= fopad) return;
    size_t o = (size_t)v * fopad + col;
    if (col >= fo) { Ohi[o] = 0; Olo[o] = 0; return; }
    int s = row_start[v], e = row_start[v + 1];
    float acc = 0.f;
    for (int i = s; i < e; ++i) {
        int u = csr_src[i];
        float h = X[(size_t)u * fo + col];
        if (WEIGH) h *= dinv_out[u];
        acc += h;
    }
    float r = acc * dinv_in[v];
    u16 hh, ll;
    bf16_split(r, hh, ll);
    Ohi[o] = hh; Olo[o] = ll;
}

// post: r = leaky(acc*dinv_in + bias) * dinv_out  (fold for next consumer)
// SPLIT: write bf16 hi/lo ; else write f32
template <bool SPLIT>
__global__ void spmm_post(
    const float* __restrict__ T, const int* __restrict__ row_start,
    const int* __restrict__ csr_src,
    const float* __restrict__ dinv_in, const float* __restrict__ dinv_out,
    const float* __restrict__ bias,
    u16* __restrict__ Ohi, u16* __restrict__ Olo, float* __restrict__ Of, int fo)
{
    int v = blockIdx.x;
    int col = blockIdx.y * blockDim.x + threadIdx.x;
    if (col >= fo) return;
    int s = row_start[v], e = row_start[v + 1];
    float acc = 0.f;
    for (int i = s; i < e; ++i) {
        int u = csr_src[i];
        acc += T[(size_t)u * fo + col];
    }
    float r = acc * dinv_in[v] + bias[col];
    r = (r > 0.f) ? r : 0.01f * r;
    r *= dinv_out[v];
    size_t o = (size_t)v * fo + col;
    if (SPLIT) {
        u16 hh, ll;
        bf16_split(r, hh, ll);
        Ohi[o] = hh; Olo[o] = ll;
    } else {
        Of[o] = r;
    }
}

// ---------------- GEMM bf16x3 MFMA: D = A @ Wt^T ----------------
// A: hi/lo bf16 [M][Ka] (k-contiguous), Wt: hi/lo bf16 [N][Ka] (k-contiguous).
// 128x128 tile, BK=32, 256 thr = 4 waves (2x2 of 64x64), 4x4 16x16x32 frags/wave.
// Fragment maps (m89-verified): A row=lane&15,k=(lane>>4)*8+e; B col=lane&15 same k;
// D col=lane&15, row=(lane>>4)*4+reg.

template <bool SPLIT_OUT>
__global__ __launch_bounds__(256) void gemm_bf3_kernel(
    const u16* __restrict__ Ahi, const u16* __restrict__ Alo,
    const u16* __restrict__ Bhi, const u16* __restrict__ Blo,
    const float* __restrict__ bias, const float* __restrict__ dfold, int relu,
    u16* __restrict__ Ohi, u16* __restrict__ Olo, float* __restrict__ Of,
    int M, int Ka, int N)
{
    // 4 buffers x 128 rows x 20 u32 (32 bf16 + pad) = 40960 B
    __shared__ u32 lds[10240];
    u32* sAh = lds;
    u32* sAl = lds + 2560;
    u32* sBh = lds + 5120;
    u32* sBl = lds + 7680;

    int tid = threadIdx.x;
    int lane = tid & 63, wave = tid >> 6;
    int wr = (wave >> 1) * 64, wc = (wave & 1) * 64;
    int bm = blockIdx.x * 128, bn = blockIdx.y * 128;

    f32x4 acc[4][4];
    #pragma unroll
    for (int i = 0; i < 4; ++i)
        #pragma unroll
        for (int j = 0; j < 4; ++j)
            acc[i][j] = (f32x4){0.f, 0.f, 0.f, 0.f};

    int sm = tid & 127, shf = tid >> 7;
    int gr = bm + sm;
    bool aok = (gr < M);
    const u16* pAh = Ahi + (size_t)(aok ? gr : 0) * Ka + shf * 16;
    const u16* pAl = Alo + (size_t)(aok ? gr : 0) * Ka + shf * 16;
    const u16* pBh = Bhi + (size_t)(bn + sm) * Ka + shf * 16;
    const u16* pBl = Blo + (size_t)(bn + sm) * Ka + shf * 16;
    int wbase = sm * 20 + shf * 8;

    int lr = lane & 15, lk = (lane >> 4) * 4;

    int nsteps = Ka >> 5;
    for (int kt = 0; kt < nsteps; ++kt) {
        size_t ko = (size_t)kt * 32;
        uint4 z = make_uint4(0, 0, 0, 0);
        uint4 vah0 = z, vah1 = z, val0 = z, val1 = z;
        if (aok) {
            vah0 = *reinterpret_cast<const uint4*>(pAh + ko);
            vah1 = *reinterpret_cast<const uint4*>(pAh + ko + 8);
            val0 = *reinterpret_cast<const uint4*>(pAl + ko);
            val1 = *reinterpret_cast<const uint4*>(pAl + ko + 8);
        }
        uint4 vbh0 = *reinterpret_cast<const uint4*>(pBh + ko);
        uint4 vbh1 = *reinterpret_cast<const uint4*>(pBh + ko + 8);
        uint4 vbl0 = *reinterpret_cast<const uint4*>(pBl + ko);
        uint4 vbl1 = *reinterpret_cast<const uint4*>(pBl + ko + 8);

        __syncthreads();  // previous step's frag reads done before overwrite
        *reinterpret_cast<uint4*>(&sAh[wbase])     = vah0;
        *reinterpret_cast<uint4*>(&sAh[wbase + 4]) = vah1;
        *reinterpret_cast<uint4*>(&sAl[wbase])     = val0;
        *reinterpret_cast<uint4*>(&sAl[wbase + 4]) = val1;
        *reinterpret_cast<uint4*>(&sBh[wbase])     = vbh0;
        *reinterpret_cast<uint4*>(&sBh[wbase + 4]) = vbh1;
        *reinterpret_cast<uint4*>(&sBl[wbase])     = vbl0;
        *reinterpret_cast<uint4*>(&sBl[wbase + 4]) = vbl1;
        __syncthreads();

        short8v ah[4], al[4], bh[4], bl[4];
        #pragma unroll
        for (int t = 0; t < 4; ++t) {
            ah[t] = *reinterpret_cast<const short8v*>(&sAh[(wr + t * 16 + lr) * 20 + lk]);
            al[t] = *reinterpret_cast<const short8v*>(&sAl[(wr + t * 16 + lr) * 20 + lk]);
            bh[t] = *reinterpret_cast<const short8v*>(&sBh[(wc + t * 16 + lr) * 20 + lk]);
            bl[t] = *reinterpret_cast<const short8v*>(&sBl[(wc + t * 16 + lr) * 20 + lk]);
        }
        #pragma unroll
        for (int i = 0; i < 4; ++i)
            #pragma unroll
            for (int j = 0; j < 4; ++j) {
                acc[i][j] = __builtin_amdgcn_mfma_f32_16x16x32_bf16(ah[i], bh[j], acc[i][j], 0, 0, 0);
                acc[i][j] = __builtin_amdgcn_mfma_f32_16x16x32_bf16(ah[i], bl[j], acc[i][j], 0, 0, 0);
                acc[i][j] = __builtin_amdgcn_mfma_f32_16x16x32_bf16(al[i], bh[j], acc[i][j], 0, 0, 0);
            }
    }

    // ---- epilogue ----
    int lq = (lane >> 4) * 4;
    float bj[4] = {0.f, 0.f, 0.f, 0.f};
    if (bias) {
        #pragma unroll
        for (int j = 0; j < 4; ++j) bj[j] = bias[bn + wc + j * 16 + lr];
    }
    #pragma unroll
    for (int i = 0; i < 4; ++i) {
        #pragma unroll
        for (int r = 0; r < 4; ++r) {
            int row = bm + wr + i * 16 + lq + r;
            if (row < M) {
                float df = 1.f;
                if (SPLIT_OUT) df = dfold[row];
                #pragma unroll
                for (int j = 0; j < 4; ++j) {
                    float v = acc[i][j][r] + bj[j];
                    if (relu) v = (v > 0.f) ? v : 0.01f * v;
                    int col = bn + wc + j * 16 + lr;
                    size_t o = (size_t)row * N + col;
                    if (SPLIT_OUT) {
                        v *= df;
                        u16 hh, ll;
                        bf16_split(v, hh, ll);
                        Ohi[o] = hh; Olo[o] = ll;
                    } else {
                        Of[o] = v;
                    }
                }
            }
        }
    }
}

// ---------------- launch ----------------

extern "C" void kernel_launch(void* const* d_in, const int* in_sizes, int n_in,
                              void* d_out, int out_size, void* d_ws, size_t ws_size,
                              hipStream_t stream) {
    const float* x = (const float*)d_in[0];
    const int* ei = (const int*)d_in[1];           // int32 (harness contract)
    const float* Wm[5] = {(const float*)d_in[2], (const float*)d_in[4], (const float*)d_in[6],
                          (const float*)d_in[8], (const float*)d_in[10]};
    const float* bv[5] = {(const float*)d_in[3], (const float*)d_in[5], (const float*)d_in[7],
                          (const float*)d_in[9], (const float*)d_in[11]};
    const int E = in_sizes[1] / 2;                 // 250000
    const int M = N_NODES;
    float* out = (float*)d_out;

    const int dims[6] = {300, 1024, 512, 256, 128, 2048};
    const int Kp[5]   = {320, 1024, 512, 256, 128};

    // ---- d_ws layout ----
    int* wsi = (int*)d_ws;
    int* deg_out   = wsi + 0;
    int* deg_in    = wsi + 50048;
    int* fill_cnt  = wsi + 100096;
    int* row_start = wsi + 150144;  // 50001 ints
    int* csr_src   = wsi + 200256;  // 250000 ints
    float* dinv_out = (float*)(wsi + 450304);
    float* dinv_in  = (float*)(wsi + 500352);
    u16* WtH = (u16*)((char*)d_ws + ((size_t)4 << 20));   // 2.56 MB
    u16* WtL = (u16*)((char*)d_ws + ((size_t)7 << 20));   // 2.56 MB
    u16* Xs5h = (u16*)((char*)d_ws + ((size_t)16 << 20)); // M*128*2 = 12.8 MB
    u16* Xs5l = Xs5h + (size_t)M * 128;                   // +12.8 MB -> ws use ~41.6 MB

    size_t wtoff[6];
    wtoff[0] = 0;
    for (int l = 0; l < 5; ++l) wtoff[l + 1] = wtoff[l] + (size_t)dims[l + 1] * Kp[l];

    // ---- d_out partitions (ping-pong) ----
    float* Bhalf = out + (size_t)M * 1024;
    u16* h1h = (u16*)out;               u16* h1l = h1h + (size_t)M * 1024;
    float* t2 = Bhalf;
    u16* h2h = (u16*)out;               u16* h2l = h2h + (size_t)M * 512;
    float* t3 = Bhalf;
    u16* h3h = (u16*)out;               u16* h3l = h3h + (size_t)M * 256;
    float* t4 = Bhalf;
    float* h4f = out;
    u16* Xs1h = (u16*)Bhalf;            u16* Xs1l = Xs1h + (size_t)M * 320;

    hipMemsetAsync(d_ws, 0, (size_t)150144 * 4, stream);

    degree_kernel<<<(E + 255) / 256, 256, 0, stream>>>(ei, deg_out, deg_in, E);
    dinv_kernel<<<(M + 255) / 256, 256, 0, stream>>>(deg_out, deg_in, dinv_out, dinv_in, M);
    scan_kernel<<<1, 1024, 0, stream>>>(deg_in, row_start, M);
    fill_kernel<<<(E + 255) / 256, 256, 0, stream>>>(ei, row_start, fill_cnt, csr_src, E);

    for (int l = 0; l < 5; ++l) {
        dim3 g(Kp[l] / 32, dims[l + 1] / 64);
        wsplit_kernel<<<g, 256, 0, stream>>>(Wm[l], WtH + wtoff[l], WtL + wtoff[l],
                                             dims[l], Kp[l], dims[l + 1]);
    }

    const int MB = (M + 127) / 128;  // 391

    // L1: spmm_pre(x) -> Xs1 ; GEMM1 -> h1 split (fold dinv_out, +b1, leaky)
    spmm_pre_split<true><<<dim3(M, 2), 256, 0, stream>>>(x, row_start, csr_src,
        dinv_out, dinv_in, Xs1h, Xs1l, 300, 320);
    gemm_bf3_kernel<true><<<dim3(MB, 8), 256, 0, stream>>>(
        Xs1h, Xs1l, WtH + wtoff[0], WtL + wtoff[0],
        bv[0], dinv_out, 1, h1h, h1l, nullptr, M, 320, 1024);

    // L2: GEMM2 -> t2 f32 ; spmm_post -> h2 split
    gemm_bf3_kernel<false><<<dim3(MB, 4), 256, 0, stream>>>(
        h1h, h1l, WtH + wtoff[1], WtL + wtoff[1],
        nullptr, nullptr, 0, nullptr, nullptr, t2, M, 1024, 512);
    spmm_post<true><<<dim3(M, 2), 256, 0, stream>>>(t2, row_start, csr_src,
        dinv_in, dinv_out, bv[1], h2h, h2l, nullptr, 512);

    // L3
    gemm_bf3_kernel<false><<<dim3(MB, 2), 256, 0, stream>>>(
        h2h, h2l, WtH + wtoff[2], WtL + wtoff[2],
        nullptr, nullptr, 0, nullptr, nullptr, t3, M, 512, 256);
    spmm_post<true><<<dim3(M, 1), 256, 0, stream>>>(t3, row_start, csr_src,
        dinv_in, dinv_out, bv[2], h3h, h3l, nullptr, 256);

    // L4 (post outputs f32 with dinv_out folded -> consumer is spmm_pre5)
    gemm_bf3_kernel<false><<<dim3(MB, 1), 256, 0, stream>>>(
        h3h, h3l, WtH + wtoff[3], WtL + wtoff[3],
        nullptr, nullptr, 0, nullptr, nullptr, t4, M, 256, 128);
    spmm_post<false><<<dim3(M, 1), 128, 0, stream>>>(t4, row_start, csr_src,
        dinv_in, dinv_out, bv[3], nullptr, nullptr, h4f, 128);

    // L5: spmm_pre(h4f, pre-folded) -> Xs5 ; GEMM5(+b5) -> full d_out
    spmm_pre_split<false><<<dim3(M, 1), 128, 0, stream>>>(h4f, row_start, csr_src,
        nullptr, dinv_in, Xs5h, Xs5l, 128, 128);
    gemm_bf3_kernel<false><<<dim3(MB, 16), 256, 0, stream>>>(
        Xs5h, Xs5l, WtH + wtoff[4], WtL + wtoff[4],
        bv[4], nullptr, 0, nullptr, nullptr, out, M, 128, 2048);
}

// Round 6
// 1393.667 us; speedup vs baseline: 1.9415x; 1.2175x over previous
//
#include <hip/hip_runtime.h>

#define N_NODES 50000

typedef __attribute__((ext_vector_type(8))) short short8v;
typedef __attribute__((ext_vector_type(4))) float f32x4;
typedef unsigned int u32;
typedef unsigned short u16;

typedef const __attribute__((address_space(1))) void* gas_t;
typedef __attribute__((address_space(3))) void* sas_t;
#define GLOAD16(g, l) __builtin_amdgcn_global_load_lds((gas_t)(g), (sas_t)(l), 16, 0, 0)

__device__ inline u16 bf16_rn(float a) {
    u32 u = __float_as_uint(a);
    return (u16)((u + 0x7FFFu + ((u >> 16) & 1u)) >> 16);
}
__device__ inline void bf16_split(float a, u16& h, u16& l) {
    h = bf16_rn(a);
    float hf = __uint_as_float(((u32)h) << 16);
    l = bf16_rn(a - hf);
}

// ---------------- degree / norm / CSR build ----------------

__global__ void degree_kernel(const int* __restrict__ ei,
                              int* __restrict__ deg_out, int* __restrict__ deg_in, int E) {
    int e = blockIdx.x * blockDim.x + threadIdx.x;
    if (e >= E) return;
    int s = ei[e];
    int d = ei[E + e];
    if (s >= 0 && s < N_NODES) atomicAdd(&deg_out[s], 1);
    if (d >= 0 && d < N_NODES) atomicAdd(&deg_in[d], 1);
}

__global__ void dinv_kernel(const int* __restrict__ deg_out, const int* __restrict__ deg_in,
                            float* __restrict__ dinv_out, float* __restrict__ dinv_in, int n) {
    int v = blockIdx.x * blockDim.x + threadIdx.x;
    if (v >= n) return;
    dinv_out[v] = rsqrtf((float)max(deg_out[v], 1));
    dinv_in[v]  = rsqrtf((float)max(deg_in[v], 1));
}

__global__ void scan_kernel(const int* __restrict__ deg, int* __restrict__ row_start, int n) {
    __shared__ int sdata[1024];
    __shared__ int carry;
    int tid = threadIdx.x;
    if (tid == 0) { carry = 0; row_start[0] = 0; }
    __syncthreads();
    for (int base = 0; base < n; base += 1024) {
        int i = base + tid;
        int v = (i < n) ? deg[i] : 0;
        sdata[tid] = v;
        __syncthreads();
        for (int off = 1; off < 1024; off <<= 1) {
            int t = (tid >= off) ? sdata[tid - off] : 0;
            __syncthreads();
            sdata[tid] += t;
            __syncthreads();
        }
        if (i < n) row_start[i + 1] = carry + sdata[tid];
        __syncthreads();
        if (tid == 0) carry += sdata[1023];
        __syncthreads();
    }
}

__global__ void fill_kernel(const int* __restrict__ ei, const int* __restrict__ row_start,
                            int* __restrict__ fill_cnt, int* __restrict__ csr_src, int E) {
    int e = blockIdx.x * blockDim.x + threadIdx.x;
    if (e >= E) return;
    int s = ei[e];
    int d = ei[E + e];
    if (d < 0 || d >= N_NODES) return;
    int pos = row_start[d] + atomicAdd(&fill_cnt[d], 1);
    csr_src[pos] = s;
}

// ---------------- W split+transpose: W[K][N] f32 -> Wt_hi/lo [N][Kp] bf16 ----------------

__global__ __launch_bounds__(256) void wsplit_kernel(
    const float* __restrict__ W, u16* __restrict__ Thi, u16* __restrict__ Tlo,
    int K, int Kp, int N)
{
    __shared__ float Ts[32][73];
    int tid = threadIdx.x;
    int k0 = blockIdx.x * 32, n0 = blockIdx.y * 64;
    int kk = tid >> 3, nn = (tid & 7) * 8;
    float4 v0 = make_float4(0.f, 0.f, 0.f, 0.f), v1 = v0;
    if (k0 + kk < K) {
        const float* p = W + (size_t)(k0 + kk) * N + n0 + nn;
        v0 = *reinterpret_cast<const float4*>(p);
        v1 = *reinterpret_cast<const float4*>(p + 4);
    }
    Ts[kk][nn + 0] = v0.x; Ts[kk][nn + 1] = v0.y; Ts[kk][nn + 2] = v0.z; Ts[kk][nn + 3] = v0.w;
    Ts[kk][nn + 4] = v1.x; Ts[kk][nn + 5] = v1.y; Ts[kk][nn + 6] = v1.z; Ts[kk][nn + 7] = v1.w;
    __syncthreads();
    int n = tid >> 2, kq = (tid & 3) * 8;
    union { u16 a[8]; uint4 q; } Uh, Ul;
    #pragma unroll
    for (int e = 0; e < 8; ++e) {
        u16 h, l;
        bf16_split(Ts[kq + e][n], h, l);
        Uh.a[e] = h; Ul.a[e] = l;
    }
    size_t off = (size_t)(n0 + n) * Kp + k0 + kq;
    *reinterpret_cast<uint4*>(Thi + off) = Uh.q;
    *reinterpret_cast<uint4*>(Tlo + off) = Ul.q;
}

// ---------------- SpMM (float4 per thread, flattened grid) ----------------
// pre: r = (sum_u X[u]*(WEIGH?dinv_out[u]:1)) * dinv_in[v]; write bf16 hi/lo
template <bool WEIGH>
__global__ __launch_bounds__(256) void spmm_pre_split4(
    const float* __restrict__ X, const int* __restrict__ row_start,
    const int* __restrict__ csr_src,
    const float* __restrict__ dinv_out, const float* __restrict__ dinv_in,
    u16* __restrict__ Ohi, u16* __restrict__ Olo, int fo4, int fo4a, int total)
{
    int gid = blockIdx.x * blockDim.x + threadIdx.x;
    if (gid >= total) return;
    int v = gid / fo4a, c4 = gid - v * fo4a;
    size_t o = (size_t)v * fo4a + c4;   // ushort4 index
    ushort4* OH = (ushort4*)Ohi;
    ushort4* OL = (ushort4*)Olo;
    if (c4 >= fo4) {
        ushort4 z = {0, 0, 0, 0};
        OH[o] = z; OL[o] = z;
        return;
    }
    int s = row_start[v], e = row_start[v + 1];
    const float4* X4 = (const float4*)X;
    float4 acc = make_float4(0.f, 0.f, 0.f, 0.f);
    for (int i = s; i < e; ++i) {
        int u = csr_src[i];
        float4 h = X4[(size_t)u * fo4 + c4];
        float w = WEIGH ? dinv_out[u] : 1.f;
        acc.x += h.x * w; acc.y += h.y * w; acc.z += h.z * w; acc.w += h.w * w;
    }
    float di = dinv_in[v];
    float r[4] = {acc.x * di, acc.y * di, acc.z * di, acc.w * di};
    ushort4 hh, ll;
    bf16_split(r[0], hh.x, ll.x); bf16_split(r[1], hh.y, ll.y);
    bf16_split(r[2], hh.z, ll.z); bf16_split(r[3], hh.w, ll.w);
    OH[o] = hh; OL[o] = ll;
}

// post: r = leaky(acc*dinv_in + bias) * dinv_out (folded for next consumer)
template <bool SPLIT>
__global__ __launch_bounds__(256) void spmm_post4(
    const float* __restrict__ T, const int* __restrict__ row_start,
    const int* __restrict__ csr_src,
    const float* __restrict__ dinv_in, const float* __restrict__ dinv_out,
    const float* __restrict__ bias,
    u16* __restrict__ Ohi, u16* __restrict__ Olo, float* __restrict__ Of,
    int fo4, int total)
{
    int gid = blockIdx.x * blockDim.x + threadIdx.x;
    if (gid >= total) return;
    int v = gid / fo4, c4 = gid - v * fo4;
    int s = row_start[v], e = row_start[v + 1];
    const float4* T4 = (const float4*)T;
    float4 acc = make_float4(0.f, 0.f, 0.f, 0.f);
    for (int i = s; i < e; ++i) {
        int u = csr_src[i];
        float4 h = T4[(size_t)u * fo4 + c4];
        acc.x += h.x; acc.y += h.y; acc.z += h.z; acc.w += h.w;
    }
    float di = dinv_in[v], dfold = dinv_out[v];
    float4 b4 = ((const float4*)bias)[c4];
    float r[4] = {acc.x * di + b4.x, acc.y * di + b4.y,
                  acc.z * di + b4.z, acc.w * di + b4.w};
    #pragma unroll
    for (int j = 0; j < 4; ++j) {
        r[j] = (r[j] > 0.f) ? r[j] : 0.01f * r[j];
        r[j] *= dfold;
    }
    size_t o = (size_t)v * fo4 + c4;
    if (SPLIT) {
        ushort4 hh, ll;
        bf16_split(r[0], hh.x, ll.x); bf16_split(r[1], hh.y, ll.y);
        bf16_split(r[2], hh.z, ll.z); bf16_split(r[3], hh.w, ll.w);
        ((ushort4*)Ohi)[o] = hh; ((ushort4*)Olo)[o] = ll;
    } else {
        ((float4*)Of)[o] = make_float4(r[0], r[1], r[2], r[3]);
    }
}

// ---------------- GEMM bf16x3 MFMA, m97 structure ----------------
// A: hi/lo bf16 [M][Ka] k-contig; Wt: hi/lo bf16 [N][Ka] k-contig.
// 128x128 tile, BK=32, 4 waves (2x2 of 64x64), 4x4 16x16x32 frags/wave.
// LDS linear [128 rows][64B] per stream (32KB total), staged via
// global_load_lds width=16 (per-lane global src, wave-uniform LDS dst).
// Last M-block: clamp source row to M-1 (valid addr, rows discarded on write).

template <bool SPLIT_OUT>
__global__ __launch_bounds__(256) void gemm_bf3_kernel(
    const u16* __restrict__ Ahi, const u16* __restrict__ Alo,
    const u16* __restrict__ Bhi, const u16* __restrict__ Blo,
    const float* __restrict__ bias, const float* __restrict__ dfold, int relu,
    u16* __restrict__ Ohi, u16* __restrict__ Olo, float* __restrict__ Of,
    int M, int Ka, int N)
{
    __shared__ u16 sAh[128 * 32];
    __shared__ u16 sAl[128 * 32];
    __shared__ u16 sBh[128 * 32];
    __shared__ u16 sBl[128 * 32];

    int tid = threadIdx.x;
    int lane = tid & 63, wave = tid >> 6;

    // XCD-bijective swizzle (m204) on A-panel-major flat id.
    int GY = gridDim.y;
    int nwg = gridDim.x * GY;
    int f = blockIdx.x * GY + blockIdx.y;
    int q = nwg >> 3, r = nwg & 7;
    int xcd = f & 7, idx = f >> 3;
    int swz = (xcd < r ? xcd * (q + 1) : r * (q + 1) + (xcd - r) * q) + idx;
    int bm = (swz / GY) * 128, bn = (swz % GY) * 128;

    int wr = (wave >> 1) * 64, wc = (wave & 1) * 64;

    f32x4 acc[4][4];
    #pragma unroll
    for (int i = 0; i < 4; ++i)
        #pragma unroll
        for (int j = 0; j < 4; ++j)
            acc[i][j] = (f32x4){0.f, 0.f, 0.f, 0.f};

    // staging geometry: chunk c in {0,1}; row128 = wave*32 + c*16 + lane/4
    int rl = lane >> 2;            // 0..15
    int qq = lane & 3;             // 16B quarter of 64B row
    int lr = lane & 15, lkb = (lane >> 4) * 8;   // fragment read coords

    int nsteps = Ka >> 5;
    for (int kt = 0; kt < nsteps; ++kt) {
        int kb = kt * 32;
        __syncthreads();   // prev step's ds_reads done before overwrite
        #pragma unroll
        for (int c = 0; c < 2; ++c) {
            int row128 = wave * 32 + c * 16 + rl;
            int grA = min(bm + row128, M - 1);
            int grB = bn + row128;
            size_t aoff = (size_t)grA * Ka + kb + qq * 8;
            size_t boff = (size_t)grB * Ka + kb + qq * 8;
            int lb = (wave * 2 + c) * 512;   // u16 units, wave-uniform
            GLOAD16(Ahi + aoff, sAh + lb);
            GLOAD16(Alo + aoff, sAl + lb);
            GLOAD16(Bhi + boff, sBh + lb);
            GLOAD16(Blo + boff, sBl + lb);
        }
        __syncthreads();   // compiler drains vmcnt before barrier

        short8v ah[4], al[4], bh[4], bl[4];
        #pragma unroll
        for (int t = 0; t < 4; ++t) {
            int ra = (wr + t * 16 + lr) * 32 + lkb;
            int rb = (wc + t * 16 + lr) * 32 + lkb;
            ah[t] = *reinterpret_cast<const short8v*>(&sAh[ra]);
            al[t] = *reinterpret_cast<const short8v*>(&sAl[ra]);
            bh[t] = *reinterpret_cast<const short8v*>(&sBh[rb]);
            bl[t] = *reinterpret_cast<const short8v*>(&sBl[rb]);
        }
        // 3 passes of 16 independent MFMAs (spread dependent chains)
        #pragma unroll
        for (int i = 0; i < 4; ++i)
            #pragma unroll
            for (int j = 0; j < 4; ++j)
                acc[i][j] = __builtin_amdgcn_mfma_f32_16x16x32_bf16(ah[i], bh[j], acc[i][j], 0, 0, 0);
        #pragma unroll
        for (int i = 0; i < 4; ++i)
            #pragma unroll
            for (int j = 0; j < 4; ++j)
                acc[i][j] = __builtin_amdgcn_mfma_f32_16x16x32_bf16(ah[i], bl[j], acc[i][j], 0, 0, 0);
        #pragma unroll
        for (int i = 0; i < 4; ++i)
            #pragma unroll
            for (int j = 0; j < 4; ++j)
                acc[i][j] = __builtin_amdgcn_mfma_f32_16x16x32_bf16(al[i], bh[j], acc[i][j], 0, 0, 0);
    }

    // ---- epilogue ----
    int lq = (lane >> 4) * 4;
    float bj[4] = {0.f, 0.f, 0.f, 0.f};
    if (bias) {
        #pragma unroll
        for (int j = 0; j < 4; ++j) bj[j] = bias[bn + wc + j * 16 + lr];
    }
    #pragma unroll
    for (int i = 0; i < 4; ++i) {
        #pragma unroll
        for (int rr = 0; rr < 4; ++rr) {
            int row = bm + wr + i * 16 + lq + rr;
            if (row < M) {
                float df = 1.f;
                if (SPLIT_OUT) df = dfold[row];
                #pragma unroll
                for (int j = 0; j < 4; ++j) {
                    float v = acc[i][j][rr] + bj[j];
                    if (relu) v = (v > 0.f) ? v : 0.01f * v;
                    int col = bn + wc + j * 16 + lr;
                    size_t o = (size_t)row * N + col;
                    if (SPLIT_OUT) {
                        v *= df;
                        u16 hh, ll;
                        bf16_split(v, hh, ll);
                        Ohi[o] = hh; Olo[o] = ll;
                    } else {
                        Of[o] = v;
                    }
                }
            }
        }
    }
}

// ---------------- launch ----------------

extern "C" void kernel_launch(void* const* d_in, const int* in_sizes, int n_in,
                              void* d_out, int out_size, void* d_ws, size_t ws_size,
                              hipStream_t stream) {
    const float* x = (const float*)d_in[0];
    const int* ei = (const int*)d_in[1];           // int32 (harness contract)
    const float* Wm[5] = {(const float*)d_in[2], (const float*)d_in[4], (const float*)d_in[6],
                          (const float*)d_in[8], (const float*)d_in[10]};
    const float* bv[5] = {(const float*)d_in[3], (const float*)d_in[5], (const float*)d_in[7],
                          (const float*)d_in[9], (const float*)d_in[11]};
    const int E = in_sizes[1] / 2;                 // 250000
    const int M = N_NODES;
    float* out = (float*)d_out;

    const int dims[6] = {300, 1024, 512, 256, 128, 2048};
    const int Kp[5]   = {320, 1024, 512, 256, 128};

    // ---- d_ws layout ----
    int* wsi = (int*)d_ws;
    int* deg_out   = wsi + 0;
    int* deg_in    = wsi + 50048;
    int* fill_cnt  = wsi + 100096;
    int* row_start = wsi + 150144;  // 50001 ints
    int* csr_src   = wsi + 200256;  // 250000 ints
    float* dinv_out = (float*)(wsi + 450304);
    float* dinv_in  = (float*)(wsi + 500352);
    u16* WtH = (u16*)((char*)d_ws + ((size_t)4 << 20));   // 2.56 MB
    u16* WtL = (u16*)((char*)d_ws + ((size_t)7 << 20));   // 2.56 MB
    u16* Xs5h = (u16*)((char*)d_ws + ((size_t)16 << 20)); // M*128 u16 = 12.8 MB
    u16* Xs5l = Xs5h + (size_t)M * 128;                   // ws use ~41.6 MB

    size_t wtoff[6];
    wtoff[0] = 0;
    for (int l = 0; l < 5; ++l) wtoff[l + 1] = wtoff[l] + (size_t)dims[l + 1] * Kp[l];

    // ---- d_out partitions (ping-pong halves) ----
    float* Bhalf = out + (size_t)M * 1024;
    u16* h1h = (u16*)out;               u16* h1l = h1h + (size_t)M * 1024;
    float* t2 = Bhalf;
    u16* h2h = (u16*)out;               u16* h2l = h2h + (size_t)M * 512;
    float* t3 = Bhalf;
    u16* h3h = (u16*)out;               u16* h3l = h3h + (size_t)M * 256;
    float* t4 = Bhalf;
    float* h4f = out;
    u16* Xs1h = (u16*)Bhalf;            u16* Xs1l = Xs1h + (size_t)M * 320;

    hipMemsetAsync(d_ws, 0, (size_t)150144 * 4, stream);

    degree_kernel<<<(E + 255) / 256, 256, 0, stream>>>(ei, deg_out, deg_in, E);
    dinv_kernel<<<(M + 255) / 256, 256, 0, stream>>>(deg_out, deg_in, dinv_out, dinv_in, M);
    scan_kernel<<<1, 1024, 0, stream>>>(deg_in, row_start, M);
    fill_kernel<<<(E + 255) / 256, 256, 0, stream>>>(ei, row_start, fill_cnt, csr_src, E);

    for (int l = 0; l < 5; ++l) {
        dim3 g(Kp[l] / 32, dims[l + 1] / 64);
        wsplit_kernel<<<g, 256, 0, stream>>>(Wm[l], WtH + wtoff[l], WtL + wtoff[l],
                                             dims[l], Kp[l], dims[l + 1]);
    }

    const int MB = (M + 127) / 128;  // 391

    // L1: spmm_pre(x,300) -> Xs1 ; GEMM1 (fold dinv_out, +b1, leaky) -> h1 split
    {
        int total = M * 80;  // fo4a = 320/4
        spmm_pre_split4<true><<<(total + 255) / 256, 256, 0, stream>>>(
            x, row_start, csr_src, dinv_out, dinv_in, Xs1h, Xs1l, 75, 80, total);
        gemm_bf3_kernel<true><<<dim3(MB, 8), 256, 0, stream>>>(
            Xs1h, Xs1l, WtH + wtoff[0], WtL + wtoff[0],
            bv[0], dinv_out, 1, h1h, h1l, nullptr, M, 320, 1024);
    }
    // L2: GEMM2 -> t2 f32 ; spmm_post -> h2 split
    gemm_bf3_kernel<false><<<dim3(MB, 4), 256, 0, stream>>>(
        h1h, h1l, WtH + wtoff[1], WtL + wtoff[1],
        nullptr, nullptr, 0, nullptr, nullptr, t2, M, 1024, 512);
    {
        int total = M * 128;
        spmm_post4<true><<<(total + 255) / 256, 256, 0, stream>>>(
            t2, row_start, csr_src, dinv_in, dinv_out, bv[1], h2h, h2l, nullptr, 128, total);
    }
    // L3
    gemm_bf3_kernel<false><<<dim3(MB, 2), 256, 0, stream>>>(
        h2h, h2l, WtH + wtoff[2], WtL + wtoff[2],
        nullptr, nullptr, 0, nullptr, nullptr, t3, M, 512, 256);
    {
        int total = M * 64;
        spmm_post4<true><<<(total + 255) / 256, 256, 0, stream>>>(
            t3, row_start, csr_src, dinv_in, dinv_out, bv[2], h3h, h3l, nullptr, 64, total);
    }
    // L4 (f32 out with dinv_out folded -> consumer is spmm_pre5)
    gemm_bf3_kernel<false><<<dim3(MB, 1), 256, 0, stream>>>(
        h3h, h3l, WtH + wtoff[3], WtL + wtoff[3],
        nullptr, nullptr, 0, nullptr, nullptr, t4, M, 256, 128);
    {
        int total = M * 32;
        spmm_post4<false><<<(total + 255) / 256, 256, 0, stream>>>(
            t4, row_start, csr_src, dinv_in, dinv_out, bv[3], nullptr, nullptr, h4f, 32, total);
    }
    // L5: spmm_pre(h4f, pre-folded) -> Xs5 ; GEMM5(+b5) -> full d_out
    {
        int total = M * 32;
        spmm_pre_split4<false><<<(total + 255) / 256, 256, 0, stream>>>(
            h4f, row_start, csr_src, nullptr, dinv_in, Xs5h, Xs5l, 32, 32, total);
        gemm_bf3_kernel<false><<<dim3(MB, 16), 256, 0, stream>>>(
            Xs5h, Xs5l, WtH + wtoff[4], WtL + wtoff[4],
            bv[4], nullptr, 0, nullptr, nullptr, out, M, 128, 2048);
    }
}